// Round 4
// baseline (471.222 us; speedup 1.0000x reference)
//
#include <hip/hip_runtime.h>
#include <hip/hip_bf16.h>
#include <stdint.h>

#define BATCH 32
#define CIN   256
#define COUT  256
#define FH    64
#define FW    64
#define NK    4
#define CTX   256
#define TEMP  30.0f

typedef __attribute__((ext_vector_type(8))) short bf16x8;
typedef __attribute__((ext_vector_type(4))) float f32x4;

__device__ __forceinline__ unsigned short f2bf(float f) {
    union { float f; uint32_t u; } a; a.f = f;
    uint32_t r = a.u + 0x7fffu + ((a.u >> 16) & 1u);
    return (unsigned short)(r >> 16);
}

// ws layout
#define WMIX_OFF  1024
#define WMIX_BYTES (32u * 9u * 8u * 4u * 256u * 16u)        // 37,748,736
#define XP_OFF    (WMIX_OFF + WMIX_BYTES)
// xp: [b][ch8][q4][y66][col68][r8] bf16  -> 32*8*4*66*68*16 B = 73,383,936

// ---------------- Kernel 1: fused prep (mix+attn | xpad) --------------------
// blocks 0..1023: expert-mix, 4 co x 2 b per block (double TLP vs 8-co).
// blocks 1024..2559: xpad, register-pack transpose, no LDS, no barriers.
__global__ __launch_bounds__(256) void prep_kernel(
        const float* __restrict__ weight,
        const float* __restrict__ g,
        const float* __restrict__ dw,
        const float* __restrict__ db,
        uint32_t* __restrict__ wmix,
        const float* __restrict__ x,
        uint32_t* __restrict__ xp) {
    __shared__ __align__(16) short S[2 * 4 * 2308];   // 36,928 B
    __shared__ float logit_s[8];
    __shared__ float att_s[8];

    const int bid = blockIdx.x;
    const int t   = threadIdx.x;

    if (bid < 1024) {
        // ================= mix part =================
        const int cog = bid & 63;                // 4 co each
        const int bg  = bid >> 6;                // 2 b each
        const int co0 = cog * 4;
        const int b0  = bg * 2;
        const size_t EST = (size_t)COUT * CIN * 9;   // 589824

        // fused attention for b0, b0+1
        {
            const int p  = t >> 5;               // pair: nb = p>>2, k = p&3
            const int i0 = t & 31;
            const int nb = p >> 2, k = p & 3;
            const float* gp = g + (size_t)(b0 + nb) * CTX;
            float part = 0.f;
#pragma unroll
            for (int j = 0; j < 8; ++j) {
                const int i = i0 + j * 32;
                part += gp[i] * dw[i * NK + k];
            }
#pragma unroll
            for (int m = 1; m <= 16; m <<= 1) part += __shfl_xor(part, m);
            if (i0 == 0) logit_s[p] = part + db[k];
        }
        __syncthreads();
        if (t < 8) {
            const int nb = t >> 2;
            const float l0 = logit_s[nb * 4 + 0] * (1.f / TEMP);
            const float l1 = logit_s[nb * 4 + 1] * (1.f / TEMP);
            const float l2 = logit_s[nb * 4 + 2] * (1.f / TEMP);
            const float l3 = logit_s[nb * 4 + 3] * (1.f / TEMP);
            const float m  = fmaxf(fmaxf(l0, l1), fmaxf(l2, l3));
            const float e0 = expf(l0 - m), e1 = expf(l1 - m);
            const float e2 = expf(l2 - m), e3 = expf(l3 - m);
            const float s  = e0 + e1 + e2 + e3;
            const int   k  = t & 3;
            const float e  = (k == 0) ? e0 : (k == 1) ? e1 : (k == 2) ? e2 : e3;
            att_s[t] = e / s;
        }
        __syncthreads();

        float a[2][4];
#pragma unroll
        for (int nb = 0; nb < 2; ++nb)
#pragma unroll
            for (int k = 0; k < 4; ++k)
                a[nb][k] = att_s[nb * 4 + k];

        // phase 1: weight -> mixed bf16 in LDS. 64 lanes per co -> 1KB runs.
        const int co_l  = t >> 6;            // 0..3
        const int inner = t & 63;            // 0..63
        const float* wbase = weight + (size_t)(co0 + co_l) * 2304;

#pragma unroll 3
        for (int i = 0; i < 9; ++i) {
            const int e4 = inner + 64 * i;   // float4 index within (k,co), 0..575
            float4 w[4];
#pragma unroll
            for (int k = 0; k < 4; ++k)
                w[k] = *(const float4*)(wbase + k * EST + (size_t)e4 * 4);
#pragma unroll
            for (int nb = 0; nb < 2; ++nb) {
                float mx = a[nb][0] * w[0].x + a[nb][1] * w[1].x + a[nb][2] * w[2].x + a[nb][3] * w[3].x;
                float my = a[nb][0] * w[0].y + a[nb][1] * w[1].y + a[nb][2] * w[2].y + a[nb][3] * w[3].y;
                float mz = a[nb][0] * w[0].z + a[nb][1] * w[1].z + a[nb][2] * w[2].z + a[nb][3] * w[3].z;
                float mw = a[nb][0] * w[0].w + a[nb][1] * w[1].w + a[nb][2] * w[2].w + a[nb][3] * w[3].w;
                uint32_t lo = (uint32_t)f2bf(mx) | ((uint32_t)f2bf(my) << 16);
                uint32_t hi = (uint32_t)f2bf(mz) | ((uint32_t)f2bf(mw) << 16);
                uint2* d = (uint2*)(S + ((nb * 4 + co_l) * 2308 + e4 * 4));
                *d = make_uint2(lo, hi);
            }
        }
        __syncthreads();

        // phase 2: LDS -> wmix, coalesced 16B stores (64B runs per 4 lanes)
        const int co_w = t & 3;
        const int slot = t >> 2;             // 0..63
#pragma unroll 3
        for (int j = 0; j < 9; ++j) {
            const int GG  = j * 64 + slot;   // 0..575 over (b_l, tap, ch, q)
            const int b_l = (GG >= 288) ? 1 : 0;
            const int rem = GG - b_l * 288;  // tap*32 + ch*4 + q
            const int tap = rem >> 5;
            const int ch  = (rem >> 2) & 7;
            const int q   = rem & 3;
            const short* sp = S + (b_l * 4 + co_w) * 2308;
            const int ebase = (ch * 32 + q * 8) * 9 + tap;
            uint32_t d[4];
#pragma unroll
            for (int rp = 0; rp < 4; ++rp) {
                uint32_t lo = (uint16_t)sp[ebase + (2 * rp) * 9];
                uint32_t hi = (uint16_t)sp[ebase + (2 * rp + 1) * 9];
                d[rp] = lo | (hi << 16);
            }
            uint32_t* dst = wmix +
                ((((size_t)((b0 + b_l) * 9 + tap) * 8 + ch) * 4 + q) * 256 + co0 + co_w) * 4;
            *(uint4*)dst = make_uint4(d[0], d[1], d[2], d[3]);
        }
    } else {
        // ================= xpad part: no LDS, register pack =================
        // thread (q = t>>6, idx = t&63); per (q,y) row: 272 dwords.
        // dword (col, rp) = pack(bf(x[ci][y-1][col-1]), bf(x[ci+1][...])),
        // ci = ch*32 + q*8 + rp*2. Stores: 256B contiguous per wave-instr.
        const int idx  = bid - 1024;         // 0..1535 = (b32, ch8, yg6)
        const int b    = idx / 48;
        const int rem2 = idx % 48;
        const int ch   = rem2 / 6;
        const int yg   = rem2 % 6;           // rows yg*11 .. yg*11+10

        const int q    = t >> 6;
        const int id64 = t & 63;

        for (int yy = 0; yy < 11; ++yy) {
            const int y = yg * 11 + yy;
            uint32_t* base = xp + (((size_t)(b * 8 + ch) * 4 + q) * 66 + y) * 272;
            if (y == 0 || y == 65) {
#pragma unroll
                for (int i = 0; i < 4; ++i) base[id64 + i * 64] = 0;
                if (id64 < 16) base[256 + id64] = 0;
            } else {
#pragma unroll
                for (int i = 0; i < 5; ++i) {
                    const int d = id64 + i * 64;
                    if (i == 4 && d >= 272) break;
                    if (d < 272) {
                        const int col = d >> 2, rp = d & 3;
                        uint32_t v = 0;
                        if (col >= 1 && col <= 64) {
                            const int ci = ch * 32 + q * 8 + rp * 2;
                            const float* p = x + ((size_t)(b * 256 + ci) * 64 + (y - 1)) * 64 + (col - 1);
                            v = (uint32_t)f2bf(p[0]) | ((uint32_t)f2bf(p[4096]) << 16);
                        }
                        base[d] = v;
                    }
                }
            }
        }
    }
}

// ---------------- Kernel 2: implicit-GEMM conv, 2-wave 128x128 tile ---------
// Block 128 thr = 2 waves. Tile 128co x 128px (2 rows). Wave: 64co x 128px
// = 4x8 of mfma_f32_16x16x32_bf16, acc 128 VGPR. 43.7 FLOP/LDS-byte (1.37x r0).
// LDS layouts interleave q at 16B so every frag read = contiguous 1KB
// (conflict-free): As[dx3][co128][q4][r8], Bs[row2][col68][q4][r8].
// Staging via global_load_lds(16B), per-lane global src handles q-planes.
__global__ __launch_bounds__(128, 2) void conv_mfma(
        const char* __restrict__ xp,
        const char* __restrict__ wmix,
        float* __restrict__ out) {
    __shared__ __align__(16) char As[3 * 8192];   // 24576 B
    __shared__ __align__(16) char Bs[2 * 4352];   //  8704 B

    const int tid  = threadIdx.x;
    const int lane = tid & 63;
    const int wv   = tid >> 6;        // 0..1: co half; also B-staging row
    const int l4   = lane >> 4;       // k-quad
    const int m16  = lane & 15;
    const int sl_co = lane >> 2;      // staging: 0..15
    const int sl_q  = lane & 3;       // staging: q

    // bijective XCD swizzle: 2048 blocks = 8 * 256
    const int bx  = blockIdx.x;
    const int wid = (bx & 7) * 256 + (bx >> 3);
    const int ptile = wid & 31;       // 0..31 -> rows y0, y0+1
    const int coT   = (wid >> 5) & 1; // 0..1
    const int b     = wid >> 6;       // 0..31
    const int y0    = ptile * 2;

    const char* wmix_b = wmix + (size_t)b * 9 * 8 * 4 * 256 * 16;
    const char* xp_b   = xp + (size_t)b * 8 * 4 * 66 * 68 * 16;

    f32x4 acc[4][8];
#pragma unroll
    for (int i = 0; i < 4; ++i)
#pragma unroll
        for (int j = 0; j < 8; ++j)
            acc[i][j] = (f32x4){0.f, 0.f, 0.f, 0.f};

    const int aOff = wv * 4096 + m16 * 64 + l4 * 16;   // + dx*8192 + sm*1024
    const int bOff = m16 * 64 + l4 * 16;               // + rr*4352 + sn*1024 + dx*64

#pragma unroll 1
    for (int ch = 0; ch < 8; ++ch) {
#pragma unroll 1
        for (int dy = 0; dy < 3; ++dy) {
            __syncthreads();   // previous phase reads done
            // ---- A staging: 24 segs of 1KB, 12 per wave ----
#pragma unroll
            for (int i = 0; i < 12; ++i) {
                const int s  = wv + i * 2;      // 0..23
                const int dx = s >> 3;
                const int cog = s & 7;
                const char* gsrc = wmix_b
                    + ((size_t)((dy * 3 + dx) * 8 + ch) * 4 + sl_q) * 4096
                    + (coT * 128 + cog * 16 + sl_co) * 16;
                char* ldst = (char*)As + dx * 8192 + cog * 1024 + lane * 16;
                __builtin_amdgcn_global_load_lds(
                    (const __attribute__((address_space(1))) void*)gsrc,
                    (__attribute__((address_space(3))) void*)ldst, 16, 0, 0);
            }
            // ---- B staging: wave wv stages row wv (4 segs + 256B tail) ----
            {
                const int yb = y0 + dy + wv;    // 0..65
                const char* grow = xp_b + ((size_t)ch * 4) * 71808 + (size_t)yb * 1088;
                char* lrow = (char*)Bs + wv * 4352;
#pragma unroll
                for (int c0 = 0; c0 < 4; ++c0) {
                    const char* gsrc = grow + (size_t)sl_q * 71808 + (c0 * 16 + sl_co) * 16;
                    char* ldst = lrow + c0 * 1024 + lane * 16;
                    __builtin_amdgcn_global_load_lds(
                        (const __attribute__((address_space(1))) void*)gsrc,
                        (__attribute__((address_space(3))) void*)ldst, 16, 0, 0);
                }
                if (lane < 16) {
                    const char* gsrc = grow + (size_t)sl_q * 71808 + (64 + sl_co) * 16;
                    char* ldst = lrow + 4096 + lane * 16;
                    __builtin_amdgcn_global_load_lds(
                        (const __attribute__((address_space(1))) void*)gsrc,
                        (__attribute__((address_space(3))) void*)ldst, 16, 0, 0);
                }
            }
            __syncthreads();   // staging visible

            // ---- compute: 3 dx K-steps x 32 MFMAs ----
#pragma unroll
            for (int dx = 0; dx < 3; ++dx) {
                bf16x8 a[4], bb[8];
#pragma unroll
                for (int sm = 0; sm < 4; ++sm)
                    a[sm] = *(const bf16x8*)((const char*)As + dx * 8192 + sm * 1024 + aOff);
#pragma unroll
                for (int rr = 0; rr < 2; ++rr)
#pragma unroll
                    for (int sn = 0; sn < 4; ++sn)
                        bb[rr * 4 + sn] = *(const bf16x8*)((const char*)Bs
                            + rr * 4352 + sn * 1024 + dx * 64 + bOff);
                __builtin_amdgcn_s_setprio(1);
#pragma unroll
                for (int sm = 0; sm < 4; ++sm)
#pragma unroll
                    for (int sn = 0; sn < 8; ++sn)
                        acc[sm][sn] = __builtin_amdgcn_mfma_f32_16x16x32_bf16(
                            a[sm], bb[sn], acc[sm][sn], 0, 0, 0);
                __builtin_amdgcn_s_setprio(0);
            }
        }
    }

    // ---- epilogue: D col=lane&15 (px), row=(lane>>4)*4+reg (co) ----
#pragma unroll
    for (int sm = 0; sm < 4; ++sm) {
#pragma unroll
        for (int rr = 0; rr < 2; ++rr) {
#pragma unroll
            for (int sn = 0; sn < 4; ++sn) {
#pragma unroll
                for (int r = 0; r < 4; ++r) {
                    const int co = coT * 128 + wv * 64 + sm * 16 + l4 * 4 + r;
                    const int y  = y0 + rr;
                    const int xx = sn * 16 + m16;
                    out[(((size_t)b * COUT + co) * FH + y) * FW + xx] = acc[sm][rr * 4 + sn][r];
                }
            }
        }
    }
}

extern "C" void kernel_launch(void* const* d_in, const int* in_sizes, int n_in,
                              void* d_out, int out_size, void* d_ws, size_t ws_size,
                              hipStream_t stream) {
    const float* x       = (const float*)d_in[0];
    const float* g       = (const float*)d_in[1];
    const float* weight  = (const float*)d_in[2];
    const float* dense_w = (const float*)d_in[3];
    const float* dense_b = (const float*)d_in[4];
    float* out = (float*)d_out;

    uint32_t* wmix = (uint32_t*)((char*)d_ws + WMIX_OFF);
    uint32_t* xp   = (uint32_t*)((char*)d_ws + XP_OFF);

    prep_kernel<<<2560, 256, 0, stream>>>(weight, g, dense_w, dense_b, wmix, x, xp);
    conv_mfma<<<2048, 128, 0, stream>>>((const char*)xp, (const char*)wmix, out);
}

// Round 5
// 383.027 us; speedup vs baseline: 1.2303x; 1.2303x over previous
//
#include <hip/hip_runtime.h>
#include <hip/hip_bf16.h>
#include <stdint.h>

#define BATCH 32
#define CIN   256
#define COUT  256
#define FH    64
#define FW    64
#define NK    4
#define CTX   256
#define TEMP  30.0f

typedef __attribute__((ext_vector_type(8))) short bf16x8;
typedef __attribute__((ext_vector_type(4))) float f32x4;

__device__ __forceinline__ unsigned short f2bf(float f) {
    union { float f; uint32_t u; } a; a.f = f;
    uint32_t r = a.u + 0x7fffu + ((a.u >> 16) & 1u);
    return (unsigned short)(r >> 16);
}

// ws layout
#define WMIX_OFF  1024
#define WMIX_BYTES (32u * 9u * 8u * 4u * 256u * 16u)        // 37,748,736
#define XP_OFF    (WMIX_OFF + WMIX_BYTES)
// xp: [b][ch8][q4][y66][col68][r8] bf16  -> 32*8*4*66*68*16 B = 73,383,936

// ---------------- Kernel 1: fused prep --------------------------------------
// blocks 0..2815: xpad (r1-proven 6-row LDS version).
// blocks 2816..3839: expert mix, 4co x 2b tiles, attention fused.
// Single dispatch => prep cost shows as ONE rocprof row (attribution).
__global__ __launch_bounds__(256) void prep_kernel(
        const float* __restrict__ weight,
        const float* __restrict__ g,
        const float* __restrict__ dw,
        const float* __restrict__ db,
        uint32_t* __restrict__ wmix,
        const float* __restrict__ x,
        uint32_t* __restrict__ xp) {
    __shared__ __align__(16) char LDSU[36928];
    __shared__ float logit_s[8];
    __shared__ float att_s[8];

    const int bid = blockIdx.x;
    const int t   = threadIdx.x;

    if (bid < 2816) {
        // ================= xpad part (r1 structure) =================
        uint32_t* P = (uint32_t*)LDSU;      // [yy6][q4][col68][rpair4] dwords
        const int yg = bid % 11;            // rows yg*6 .. yg*6+5
        const int r2 = bid / 11;
        const int ch = r2 & 7;
        const int b  = r2 >> 3;

        for (int i = t; i < 6 * 1088; i += 256) P[i] = 0;
        __syncthreads();

        const int ci_l = t >> 3;            // 0..31
        const int col0 = (t & 7) * 8;       // 0..56
        const int q = ci_l >> 3, r = ci_l & 7;
        unsigned short* Ps = (unsigned short*)P;

#pragma unroll
        for (int yy = 0; yy < 6; ++yy) {
            const int y = yg * 6 + yy;
            if (y >= 1 && y <= 64) {
                const float* xr = x + (((size_t)(b * 256 + ch * 32 + ci_l) * 64) + (y - 1)) * 64 + col0;
                float4 v0 = *(const float4*)xr;
                float4 v1 = *(const float4*)(xr + 4);
                unsigned short bf[8];
                bf[0] = f2bf(v0.x); bf[1] = f2bf(v0.y); bf[2] = f2bf(v0.z); bf[3] = f2bf(v0.w);
                bf[4] = f2bf(v1.x); bf[5] = f2bf(v1.y); bf[6] = f2bf(v1.z); bf[7] = f2bf(v1.w);
#pragma unroll
                for (int j = 0; j < 8; ++j)
                    Ps[yy * 2176 + (q * 68 + (col0 + j + 1)) * 8 + r] = bf[j];
            }
        }
        __syncthreads();

        const int qo = t >> 6, l = t & 63;
#pragma unroll
        for (int yy = 0; yy < 6; ++yy) {
            const int y = yg * 6 + yy;
            uint32_t* base = xp + (((((size_t)(b * 8 + ch) * 4 + qo) * 66) + y) * 68) * 4;
#pragma unroll
            for (int i = 0; i < 4; ++i)
                base[l + i * 64] = P[yy * 1088 + qo * 272 + l + i * 64];
            if (l < 16) base[l + 256] = P[yy * 1088 + qo * 272 + l + 256];
        }
    } else {
        // ================= mix part (4co x 2b, fused attention) ==============
        short* S = (short*)LDSU;            // [nb2][co4][2308]
        const int mb  = bid - 2816;
        const int cog = mb & 63;            // 4 co each
        const int bg  = mb >> 6;            // 2 b each
        const int co0 = cog * 4;
        const int b0  = bg * 2;
        const size_t EST = (size_t)COUT * CIN * 9;   // 589824

        // fused attention for b0, b0+1
        {
            const int p  = t >> 5;          // pair: nb = p>>2, k = p&3
            const int i0 = t & 31;
            const int nb = p >> 2, k = p & 3;
            const float* gp = g + (size_t)(b0 + nb) * CTX;
            float part = 0.f;
#pragma unroll
            for (int j = 0; j < 8; ++j) {
                const int i = i0 + j * 32;
                part += gp[i] * dw[i * NK + k];
            }
#pragma unroll
            for (int m = 1; m <= 16; m <<= 1) part += __shfl_xor(part, m);
            if (i0 == 0) logit_s[p] = part + db[k];
        }
        __syncthreads();
        if (t < 8) {
            const int nb = t >> 2;
            const float l0 = logit_s[nb * 4 + 0] * (1.f / TEMP);
            const float l1 = logit_s[nb * 4 + 1] * (1.f / TEMP);
            const float l2 = logit_s[nb * 4 + 2] * (1.f / TEMP);
            const float l3 = logit_s[nb * 4 + 3] * (1.f / TEMP);
            const float m  = fmaxf(fmaxf(l0, l1), fmaxf(l2, l3));
            const float e0 = expf(l0 - m), e1 = expf(l1 - m);
            const float e2 = expf(l2 - m), e3 = expf(l3 - m);
            const float s  = e0 + e1 + e2 + e3;
            const int   k  = t & 3;
            const float e  = (k == 0) ? e0 : (k == 1) ? e1 : (k == 2) ? e2 : e3;
            att_s[t] = e / s;
        }
        __syncthreads();

        float a[2][4];
#pragma unroll
        for (int nb = 0; nb < 2; ++nb)
#pragma unroll
            for (int k = 0; k < 4; ++k)
                a[nb][k] = att_s[nb * 4 + k];

        // phase 1: weight -> mixed bf16 in LDS. 64 lanes per co -> 1KB runs.
        const int co_l  = t >> 6;           // 0..3
        const int inner = t & 63;           // 0..63
        const float* wbase = weight + (size_t)(co0 + co_l) * 2304;

#pragma unroll 3
        for (int i = 0; i < 9; ++i) {
            const int e4 = inner + 64 * i;  // float4 index within (k,co), 0..575
            float4 w[4];
#pragma unroll
            for (int k = 0; k < 4; ++k)
                w[k] = *(const float4*)(wbase + k * EST + (size_t)e4 * 4);
#pragma unroll
            for (int nb = 0; nb < 2; ++nb) {
                float mx = a[nb][0] * w[0].x + a[nb][1] * w[1].x + a[nb][2] * w[2].x + a[nb][3] * w[3].x;
                float my = a[nb][0] * w[0].y + a[nb][1] * w[1].y + a[nb][2] * w[2].y + a[nb][3] * w[3].y;
                float mz = a[nb][0] * w[0].z + a[nb][1] * w[1].z + a[nb][2] * w[2].z + a[nb][3] * w[3].z;
                float mw = a[nb][0] * w[0].w + a[nb][1] * w[1].w + a[nb][2] * w[2].w + a[nb][3] * w[3].w;
                uint32_t lo = (uint32_t)f2bf(mx) | ((uint32_t)f2bf(my) << 16);
                uint32_t hi = (uint32_t)f2bf(mz) | ((uint32_t)f2bf(mw) << 16);
                uint2* d = (uint2*)(S + ((nb * 4 + co_l) * 2308 + e4 * 4));
                *d = make_uint2(lo, hi);
            }
        }
        __syncthreads();

        // phase 2: LDS -> wmix, coalesced 16B stores
        const int co_w = t & 3;
        const int slot = t >> 2;            // 0..63
#pragma unroll 3
        for (int j = 0; j < 9; ++j) {
            const int GG  = j * 64 + slot;  // 0..575 over (b_l, tap, ch, q)
            const int b_l = (GG >= 288) ? 1 : 0;
            const int rem = GG - b_l * 288; // tap*32 + ch*4 + q
            const int tap = rem >> 5;
            const int ch  = (rem >> 2) & 7;
            const int q   = rem & 3;
            const short* sp = S + (b_l * 4 + co_w) * 2308;
            const int ebase = (ch * 32 + q * 8) * 9 + tap;
            uint32_t d[4];
#pragma unroll
            for (int rp = 0; rp < 4; ++rp) {
                uint32_t lo = (uint16_t)sp[ebase + (2 * rp) * 9];
                uint32_t hi = (uint16_t)sp[ebase + (2 * rp + 1) * 9];
                d[rp] = lo | (hi << 16);
            }
            uint32_t* dst = wmix +
                ((((size_t)((b0 + b_l) * 9 + tap) * 8 + ch) * 4 + q) * 256 + co0 + co_w) * 4;
            *(uint4*)dst = make_uint4(d[0], d[1], d[2], d[3]);
        }
    }
}

// ---------------- Kernel 2: implicit-GEMM conv (r0 structure + XCD swz) -----
// Block 256 thr (4 waves, 2co x 2px). Tile 128co x 128px (rows y0,y0+1).
// Wave: 64co x 64px = 4x4 of mfma_f32_16x16x32_bf16.
// Phase = (ci-chunk of 32) x (dy): stage A 24.6KB + B 8.7KB via
// global_load_lds(16B), then 3 dx K-steps of 16 MFMAs. (= the 153 us r0 conv)
__global__ __launch_bounds__(256, 3) void conv_mfma(
        const char* __restrict__ xp,
        const char* __restrict__ wmix,
        float* __restrict__ out) {
    __shared__ __align__(16) short As[3 * 4 * 128 * 8];   // 24576 B [dx][q][co128][r8]
    __shared__ __align__(16) short Bs[4 * 2 * 68 * 8];    //  8704 B [q][row2][col68][r8]

    const int tid  = threadIdx.x;
    const int lane = tid & 63;
    const int wv   = tid >> 6;
    const int wm   = wv & 1;          // co half
    const int wn   = wv >> 1;         // px half == image row offset
    const int l4   = lane >> 4;       // k-quad
    const int m16  = lane & 15;

    // bijective XCD swizzle: 2048 blocks = 8 XCD * 256; XCD keeps 4 batches
    const int bx  = blockIdx.x;
    const int wid = (bx & 7) * 256 + (bx >> 3);
    const int ptile = wid & 31;       // 0..31
    const int coT   = (wid >> 5) & 1; // 0..1
    const int b     = wid >> 6;       // 0..31
    const int y0    = ptile * 2;

    const char* wmix_b = wmix + (size_t)b * 9 * 8 * 4 * 256 * 16;
    const char* xp_b   = xp + (size_t)b * 8 * 4 * 66 * 68 * 16;

    f32x4 acc[4][4];
#pragma unroll
    for (int i = 0; i < 4; ++i)
#pragma unroll
        for (int j = 0; j < 4; ++j)
            acc[i][j] = (f32x4){0.f, 0.f, 0.f, 0.f};

    const int aLane = l4 * 2048 + wm * 1024 + m16 * 16;   // byte off in As
    const int bLane = l4 * 2176 + wn * 1088 + m16 * 16;   // byte off in Bs

#pragma unroll 1
    for (int ch = 0; ch < 8; ++ch) {
#pragma unroll 1
        for (int dy = 0; dy < 3; ++dy) {
            __syncthreads();   // previous phase reads done
            // ---- A staging: 24 segments of 1KB (6 per wave) ----
#pragma unroll
            for (int i = 0; i < 6; ++i) {
                const int s  = wv + i * 4;      // 0..23
                const int dx = s >> 3;
                const int q  = (s >> 1) & 3;
                const int h  = s & 1;
                const char* gsrc = wmix_b
                    + ((size_t)((dy * 3 + dx) * 8 + ch) * 4 + q) * 4096
                    + (coT * 128 + h * 64 + lane) * 16;
                char* ldst = (char*)As + ((dx * 4 + q) * 128 + h * 64 + lane) * 16;
                __builtin_amdgcn_global_load_lds(
                    (const __attribute__((address_space(1))) void*)gsrc,
                    (__attribute__((address_space(3))) void*)ldst, 16, 0, 0);
            }
            // ---- B staging: wave wv stages q=wv, rows yb..yb+1 (2176 B) ----
            {
                const int yb = y0 + dy;     // padded-row index, 0..64
                const char* gsrc = xp_b
                    + (((size_t)ch * 4 + wv) * 66 + yb) * 1088 + lane * 16;
                char* ldst = (char*)Bs + wv * 2176 + lane * 16;
                __builtin_amdgcn_global_load_lds(
                    (const __attribute__((address_space(1))) void*)gsrc,
                    (__attribute__((address_space(3))) void*)ldst, 16, 0, 0);
                __builtin_amdgcn_global_load_lds(
                    (const __attribute__((address_space(1))) void*)(gsrc + 1024),
                    (__attribute__((address_space(3))) void*)(ldst + 1024), 16, 0, 0);
                if (lane < 8)
                    __builtin_amdgcn_global_load_lds(
                        (const __attribute__((address_space(1))) void*)(gsrc + 2048),
                        (__attribute__((address_space(3))) void*)(ldst + 2048), 16, 0, 0);
            }
            __syncthreads();   // staging visible

            // ---- compute: 3 dx K-steps x 16 MFMAs ----
#pragma unroll
            for (int dx = 0; dx < 3; ++dx) {
                bf16x8 a[4], bb[4];
#pragma unroll
                for (int sm = 0; sm < 4; ++sm)
                    a[sm] = *(const bf16x8*)((const char*)As + dx * 8192 + aLane + sm * 256);
#pragma unroll
                for (int sn = 0; sn < 4; ++sn)
                    bb[sn] = *(const bf16x8*)((const char*)Bs + bLane + dx * 16 + sn * 256);
#pragma unroll
                for (int sm = 0; sm < 4; ++sm)
#pragma unroll
                    for (int sn = 0; sn < 4; ++sn)
                        acc[sm][sn] = __builtin_amdgcn_mfma_f32_16x16x32_bf16(
                            a[sm], bb[sn], acc[sm][sn], 0, 0, 0);
            }
        }
    }

    // ---- epilogue: D col=lane&15 (px), row=(lane>>4)*4+reg (co) ----
    const int y = y0 + wn;
#pragma unroll
    for (int sm = 0; sm < 4; ++sm) {
#pragma unroll
        for (int sn = 0; sn < 4; ++sn) {
#pragma unroll
            for (int r = 0; r < 4; ++r) {
                const int co = coT * 128 + wm * 64 + sm * 16 + l4 * 4 + r;
                const int xx = sn * 16 + m16;
                out[(((size_t)b * COUT + co) * FH + y) * FW + xx] = acc[sm][sn][r];
            }
        }
    }
}

extern "C" void kernel_launch(void* const* d_in, const int* in_sizes, int n_in,
                              void* d_out, int out_size, void* d_ws, size_t ws_size,
                              hipStream_t stream) {
    const float* x       = (const float*)d_in[0];
    const float* g       = (const float*)d_in[1];
    const float* weight  = (const float*)d_in[2];
    const float* dense_w = (const float*)d_in[3];
    const float* dense_b = (const float*)d_in[4];
    float* out = (float*)d_out;

    uint32_t* wmix = (uint32_t*)((char*)d_ws + WMIX_OFF);
    uint32_t* xp   = (uint32_t*)((char*)d_ws + XP_OFF);

    prep_kernel<<<3840, 256, 0, stream>>>(weight, g, dense_w, dense_b, wmix, x, xp);
    conv_mfma<<<2048, 256, 0, stream>>>((const char*)xp, (const char*)wmix, out);
}